// Round 7
// baseline (278.150 us; speedup 1.0000x reference)
//
#include <hip/hip_runtime.h>
#include <stdint.h>

#define K_TOP 4096
#define CAP 8192            // candidate buffer (pow2, >= K_TOP + ties margin)

// ---- workspace layout (bytes) ----
static constexpr size_t HIST1_OFF = 0;                                   // 4096 u32 = 16 KB
static constexpr size_t HIST2_OFF = 16384;                               // 4096 u32 = 16 KB
static constexpr size_t SCAL_OFF  = 32768;                               // 64 B scalars
static constexpr size_t CAND_OFF  = 32832;                               // CAP u64 = 64 KB
static constexpr size_t TBOX_OFF  = CAND_OFF + (size_t)CAP * 8;          // K float4 = 64 KB
static constexpr size_t TSC_OFF   = TBOX_OFF + (size_t)K_TOP * 16;       // K float = 16 KB
static constexpr size_t MASK_OFF  = TSC_OFF + (size_t)K_TOP * 4;         // K*64 u64 = 2 MB
static constexpr size_t KEEP_OFF  = MASK_OFF + (size_t)K_TOP * 64 * 8;   // 64 u64
static constexpr size_t WS_NEED   = KEEP_OFF + 512;

// scal slots: [0]=B1 [1]=A1(count above B1) [4]=T24 threshold [5]=compact counter

typedef unsigned long long u64;

__device__ __forceinline__ unsigned ord_of(float s) {
    unsigned u = __float_as_uint(s);
    return (u & 0x80000000u) ? ~u : (u | 0x80000000u);
}

__device__ __forceinline__ u64 readlane64(u64 v, int l) {
    unsigned lo = (unsigned)__builtin_amdgcn_readlane((int)(unsigned)v, l);
    unsigned hi = (unsigned)__builtin_amdgcn_readlane((int)(v >> 32), l);
    return ((u64)hi << 32) | lo;
}

// P1: 12-bit histogram (bits 31..20 of ordered score), float4 loads, LDS-privatized
__global__ void k_hist1(const float* __restrict__ scores, unsigned* __restrict__ hist, int n) {
    __shared__ unsigned h[4096];
    for (int j = threadIdx.x; j < 4096; j += 256) h[j] = 0;
    __syncthreads();
    int gid = blockIdx.x * blockDim.x + threadIdx.x;
    int stride = gridDim.x * blockDim.x;
    int n4 = n >> 2;
    const float4* s4 = (const float4*)scores;
    for (int i = gid; i < n4; i += stride) {
        float4 v = s4[i];
        atomicAdd(&h[ord_of(v.x) >> 20], 1u);
        atomicAdd(&h[ord_of(v.y) >> 20], 1u);
        atomicAdd(&h[ord_of(v.z) >> 20], 1u);
        atomicAdd(&h[ord_of(v.w) >> 20], 1u);
    }
    for (int t = (n4 << 2) + gid; t < n; t += stride)
        atomicAdd(&h[ord_of(scores[t]) >> 20], 1u);
    __syncthreads();
    for (int j = threadIdx.x; j < 4096; j += 256) {
        unsigned v = h[j];
        if (v) atomicAdd(&hist[j], v);
    }
}

// P2: 12-bit histogram of bits 19..8 among elements whose top-12 == B1
__global__ void k_hist2(const float* __restrict__ scores, const unsigned* __restrict__ scal,
                        unsigned* __restrict__ hist, int n) {
    __shared__ unsigned h[4096];
    for (int j = threadIdx.x; j < 4096; j += 256) h[j] = 0;
    __syncthreads();
    unsigned B1 = scal[0];
    int gid = blockIdx.x * blockDim.x + threadIdx.x;
    int stride = gridDim.x * blockDim.x;
    int n4 = n >> 2;
    const float4* s4 = (const float4*)scores;
    for (int i = gid; i < n4; i += stride) {
        float4 v = s4[i];
        unsigned o0 = ord_of(v.x), o1 = ord_of(v.y), o2 = ord_of(v.z), o3 = ord_of(v.w);
        if ((o0 >> 20) == B1) atomicAdd(&h[(o0 >> 8) & 4095u], 1u);
        if ((o1 >> 20) == B1) atomicAdd(&h[(o1 >> 8) & 4095u], 1u);
        if ((o2 >> 20) == B1) atomicAdd(&h[(o2 >> 8) & 4095u], 1u);
        if ((o3 >> 20) == B1) atomicAdd(&h[(o3 >> 8) & 4095u], 1u);
    }
    for (int t = (n4 << 2) + gid; t < n; t += stride) {
        unsigned o = ord_of(scores[t]);
        if ((o >> 20) == B1) atomicAdd(&h[(o >> 8) & 4095u], 1u);
    }
    __syncthreads();
    for (int j = threadIdx.x; j < 4096; j += 256) {
        unsigned v = h[j];
        if (v) atomicAdd(&hist[j], v);
    }
}

// select threshold bin from a 4096-bin histogram via suffix scan
__global__ __launch_bounds__(1024) void k_select(const unsigned* __restrict__ hist,
                                                 unsigned* __restrict__ scal, int pass) {
    __shared__ unsigned buf[1024];
    int t = threadIdx.x;
    unsigned c0 = hist[t * 4 + 0], c1 = hist[t * 4 + 1];
    unsigned c2 = hist[t * 4 + 2], c3 = hist[t * 4 + 3];
    unsigned mysum = c0 + c1 + c2 + c3;
    buf[t] = mysum;
    __syncthreads();
    for (int off = 1; off < 1024; off <<= 1) {
        unsigned v = buf[t] + ((t + off < 1024) ? buf[t + off] : 0u);
        __syncthreads();
        buf[t] = v;
        __syncthreads();
    }
    unsigned target = (pass == 0) ? (unsigned)K_TOP : ((unsigned)K_TOP - scal[1]);
    unsigned sfx = buf[t];
    unsigned nxt = (t < 1023) ? buf[t + 1] : 0u;
    if (sfx >= target && nxt < target) {
        unsigned above = nxt;  // count in bins strictly above this 4-bin group
        unsigned b;
        if (above + c3 >= target)                { b = t * 4 + 3; }
        else if (above + c3 + c2 >= target)      { above += c3;           b = t * 4 + 2; }
        else if (above + c3 + c2 + c1 >= target) { above += c3 + c2;      b = t * 4 + 1; }
        else                                     { above += c3 + c2 + c1; b = t * 4 + 0; }
        if (pass == 0) { scal[0] = b; scal[1] = above; }
        else           { scal[4] = (scal[0] << 12) | b; }
    }
}

// compact all elements with 24-bit prefix >= T24, block-aggregated, float4 loads
__global__ __launch_bounds__(256) void k_compact(const float* __restrict__ scores,
                                                 const unsigned* __restrict__ scal,
                                                 u64* __restrict__ cand,
                                                 unsigned* __restrict__ counter, int n) {
    __shared__ unsigned lcount, lbase;
    __shared__ u64 lbuf[4096];
    if (threadIdx.x == 0) lcount = 0;
    __syncthreads();
    unsigned T = scal[4];
    int gid = blockIdx.x * blockDim.x + threadIdx.x;
    int stride = gridDim.x * blockDim.x;
    int n4 = n >> 2;
    const float4* s4 = (const float4*)scores;
    for (int i = gid; i < n4; i += stride) {
        float4 v = s4[i];
        unsigned o0 = ord_of(v.x), o1 = ord_of(v.y), o2 = ord_of(v.z), o3 = ord_of(v.w);
        int base = i << 2;
        if ((o0 >> 8) >= T) lbuf[atomicAdd(&lcount, 1u)] = ((u64)o0 << 32) | (unsigned)(~(base + 0));
        if ((o1 >> 8) >= T) lbuf[atomicAdd(&lcount, 1u)] = ((u64)o1 << 32) | (unsigned)(~(base + 1));
        if ((o2 >> 8) >= T) lbuf[atomicAdd(&lcount, 1u)] = ((u64)o2 << 32) | (unsigned)(~(base + 2));
        if ((o3 >> 8) >= T) lbuf[atomicAdd(&lcount, 1u)] = ((u64)o3 << 32) | (unsigned)(~(base + 3));
    }
    for (int t = (n4 << 2) + gid; t < n; t += stride) {
        unsigned o = ord_of(scores[t]);
        if ((o >> 8) >= T) lbuf[atomicAdd(&lcount, 1u)] = ((u64)o << 32) | (unsigned)(~t);
    }
    __syncthreads();
    if (threadIdx.x == 0) lbase = atomicAdd(counter, lcount);
    __syncthreads();
    for (unsigned j = threadIdx.x; j < lcount; j += 256) {
        unsigned p = lbase + j;
        if (p < CAP) cand[p] = lbuf[j];
    }
}

__device__ __forceinline__ float4 decode_clip(float4 a, float4 d) {
#pragma clang fp contract(off)
    const float BBOX_CLIP = (float)4.135166556742356;  // log(1000/16)
    float w  = a.z - a.x;
    float h  = a.w - a.y;
    float cx = a.x + 0.5f * w;
    float cy = a.y + 0.5f * h;
    float dx = d.x / 10.0f;
    float dy = d.y / 10.0f;
    float dw = fminf(d.z / 5.0f, BBOX_CLIP);
    float dh = fminf(d.w / 5.0f, BBOX_CLIP);
    float pcx = dx * w + cx;
    float pcy = dy * h + cy;
    float pw = (float)exp((double)dw) * w;
    float ph = (float)exp((double)dh) * h;
    float x1 = pcx - 0.5f * pw;
    float y1 = pcy - 0.5f * ph;
    float x2 = pcx + 0.5f * pw;
    float y2 = pcy + 0.5f * ph;
    x1 = fminf(fmaxf(x1, 0.0f), 1333.0f);
    y1 = fminf(fmaxf(y1, 0.0f), 800.0f);
    x2 = fminf(fmaxf(x2, 0.0f), 1333.0f);
    y2 = fminf(fmaxf(y2, 0.0f), 800.0f);
    return make_float4(x1, y1, x2, y2);
}

// rank-by-counting over candidates; decode straight into rank slot.
__global__ __launch_bounds__(256) void k_rank_gather(
        const float* __restrict__ scores, const float* __restrict__ anchors,
        const float* __restrict__ deltas, const u64* __restrict__ cand,
        const unsigned* __restrict__ scal, float4* __restrict__ tbox, float* __restrict__ tsc) {
    __shared__ u64 chunk[256];
    int t = threadIdx.x;
    int j = blockIdx.x * 256 + t;
    unsigned M = scal[5];
    if (M > CAP) M = CAP;
    u64 mykey = (j < (int)M) ? cand[j] : 0ULL;
    unsigned rank = 0;
    for (unsigned base = 0; base < M; base += 256) {
        unsigned idx = base + t;
        chunk[t] = (idx < M) ? cand[idx] : 0ULL;  // pad 0 < any valid key
        __syncthreads();
#pragma unroll 8
        for (int c = 0; c < 256; ++c) rank += (chunk[c] > mykey);
        __syncthreads();
    }
    if (j < (int)M && rank < K_TOP) {
        unsigned idx = ~(unsigned)mykey;
        float4 a = ((const float4*)anchors)[idx];
        float4 d = ((const float4*)deltas)[idx];
        tbox[rank] = decode_clip(a, d);
        tsc[rank]  = scores[idx];
    }
}

// suppression masks, upper-triangle blocks only.
__global__ void k_mask(const float4* __restrict__ tbox, u64* __restrict__ mask) {
#pragma clang fp contract(off)
    int w = blockIdx.x;  // column word (64 cols)
    int r = blockIdx.y;  // row block
    int t = threadIdx.x;
    if (w < r) return;
    int i = r * 64 + t;
    __shared__ float4 cb[64];
    __shared__ float  ca[64];
    float4 b = tbox[w * 64 + t];
    cb[t] = b;
    ca[t] = (b.z - b.x) * (b.w - b.y);
    __syncthreads();
    float4 bi = tbox[i];
    float ai = (bi.z - bi.x) * (bi.w - bi.y);
    u64 bits = 0ULL;
    for (int c = 0; c < 64; ++c) {
        int j = w * 64 + c;
        if (j > i) {
            float4 bj = cb[c];
            float ltx = fmaxf(bi.x, bj.x);
            float lty = fmaxf(bi.y, bj.y);
            float rbx = fminf(bi.z, bj.z);
            float rby = fminf(bi.w, bj.w);
            float ww = fmaxf(rbx - ltx, 0.0f);
            float hh = fmaxf(rby - lty, 0.0f);
            float inter = ww * hh;
            float denom = ((ai + ca[c]) - inter) + 1e-9f;
            float iou = inter / denom;
            if (iou > 0.7f) bits |= (1ULL << c);
        }
    }
    mask[(size_t)i * 64 + w] = bits;
}

// Single-wave greedy NMS, LDS-staged via global_load_lds (zero VGPR pipeline
// state) + counted vmcnt. lane l owns column word l. Triple-buffered LDS,
// 2 blocks (64 loads) in flight. Diag word of row r == lane b's copy of that
// row, so chain+apply fuse into one pass (readlane from the row registers).
// Lower-triangle garbage is masked by the lane>=b guard at apply time.
__global__ __launch_bounds__(64, 1) void k_nms(const u64* __restrict__ mask,
                                               u64* __restrict__ keep) {
    __shared__ u64 lbuf[3][64][64];   // 96 KB
    const int lane = threadIdx.x;
    // lane l covers row parity (l>>5), word pair (l&31)*2 of each 1KB sub-load
    const char* gbase = (const char*)mask + ((lane >> 5) << 9) + ((lane & 31) << 4);
    u64 remv = 0ULL;

    // stage block b into lbuf[b%3]: 32 x global_load_lds(16B/lane) = 64 rows
    #define STAGE(b) do {                                                      \
        const char* s_ = gbase + (size_t)(b) * 32768;                          \
        int p_ = (b) % 3;                                                      \
        _Pragma("unroll")                                                      \
        for (int j_ = 0; j_ < 32; ++j_)                                        \
            __builtin_amdgcn_global_load_lds(                                  \
                (const unsigned int*)(s_ + j_ * 1024),                         \
                (unsigned int*)&lbuf[p_][j_ * 2][0], 16, 0, 0);                \
    } while (0)

    #define WAITN(n) do {                                                      \
        asm volatile("s_waitcnt vmcnt(" #n ")" ::: "memory");                  \
        __builtin_amdgcn_sched_barrier(0);                                     \
    } while (0)

    #define LOADB(X, p, k0) do {                                               \
        _Pragma("unroll")                                                      \
        for (int r_ = 0; r_ < 8; ++r_) X[r_] = lbuf[p][(k0) + r_][lane];       \
    } while (0)

    // 8 fused chain+apply steps: bit c of w_ is final before step c uses it
    #define DO8(X, k0) do {                                                    \
        _Pragma("unroll")                                                      \
        for (int r_ = 0; r_ < 8; ++r_) {                                       \
            u64 dc_ = readlane64(X[r_], bb);                                   \
            u64 kb_ = (w_ >> ((k0) + r_)) & 1ULL;                              \
            w_ &= ~(dc_ & (0ULL - kb_));                                       \
            remv |= guard & (0ULL - kb_) & X[r_];                              \
        }                                                                      \
    } while (0)

    STAGE(0); STAGE(1);
    for (int bb = 0; bb < 64; ++bb) {
        if (bb < 62)       { WAITN(32); STAGE(bb + 2); }
        else if (bb == 62) { WAITN(32); }
        else               { WAITN(0);  }
        const int p = bb % 3;
        u64 w_ = ~readlane64(remv, bb);
        u64 guard = (lane >= bb) ? ~0ULL : 0ULL;
        u64 A[8], B[8], C[8];
        LOADB(A, p, 0);  LOADB(B, p, 8);
        LOADB(C, p, 16); DO8(A, 0);
        LOADB(A, p, 24); DO8(B, 8);
        LOADB(B, p, 32); DO8(C, 16);
        LOADB(C, p, 40); DO8(A, 24);
        LOADB(A, p, 48); DO8(B, 32);
        LOADB(B, p, 56); DO8(C, 40);
        DO8(A, 48);
        DO8(B, 56);
    }
    keep[lane] = ~remv;

    #undef STAGE
    #undef WAITN
    #undef LOADB
    #undef DO8
}

// write [K,5] output
__global__ void k_out(const float4* __restrict__ tbox, const float* __restrict__ tsc,
                      const u64* __restrict__ keep, float* __restrict__ out) {
    int j = blockIdx.x * blockDim.x + threadIdx.x;
    if (j >= K_TOP) return;
    bool kp = (keep[j >> 6] >> (j & 63)) & 1ULL;
    float4 b = tbox[j];
    float sc = tsc[j];
    float* o = out + (size_t)j * 5;
    o[0] = kp ? b.x : 0.0f;
    o[1] = kp ? b.y : 0.0f;
    o[2] = kp ? b.z : 0.0f;
    o[3] = kp ? b.w : 0.0f;
    o[4] = kp ? sc  : 0.0f;
}

extern "C" void kernel_launch(void* const* d_in, const int* in_sizes, int n_in,
                              void* d_out, int out_size, void* d_ws, size_t ws_size,
                              hipStream_t stream) {
    if (ws_size < WS_NEED) return;  // fail loudly (output stays poisoned)
    const float* scores  = (const float*)d_in[0];
    const float* anchors = (const float*)d_in[1];
    const float* deltas  = (const float*)d_in[2];
    int n = in_sizes[0];

    char* ws = (char*)d_ws;
    unsigned* hist1 = (unsigned*)(ws + HIST1_OFF);
    unsigned* hist2 = (unsigned*)(ws + HIST2_OFF);
    unsigned* scal  = (unsigned*)(ws + SCAL_OFF);
    u64* cand       = (u64*)(ws + CAND_OFF);
    float4* tbox    = (float4*)(ws + TBOX_OFF);
    float* tsc      = (float*)(ws + TSC_OFF);
    u64* mask       = (u64*)(ws + MASK_OFF);
    u64* keep       = (u64*)(ws + KEEP_OFF);

    hipMemsetAsync(ws, 0, SCAL_OFF + 64, stream);  // hist1 + hist2 + scalars

    k_hist1<<<256, 256, 0, stream>>>(scores, hist1, n);
    k_select<<<1, 1024, 0, stream>>>(hist1, scal, 0);
    k_hist2<<<256, 256, 0, stream>>>(scores, scal, hist2, n);
    k_select<<<1, 1024, 0, stream>>>(hist2, scal, 1);
    k_compact<<<256, 256, 0, stream>>>(scores, scal, cand, &scal[5], n);
    k_rank_gather<<<CAP / 256, 256, 0, stream>>>(scores, anchors, deltas, cand, scal, tbox, tsc);
    k_mask<<<dim3(64, 64), 64, 0, stream>>>(tbox, mask);
    k_nms<<<1, 64, 0, stream>>>(mask, keep);
    k_out<<<16, 256, 0, stream>>>(tbox, tsc, keep, (float*)d_out);
}